// Round 8
// baseline (608.992 us; speedup 1.0000x reference)
//
#include <hip/hip_runtime.h>
#include <hip/hip_bf16.h>
#include <math.h>

// ---------------------------------------------------------------------------
// MPNN node classifier.
// R7: (a) non-temporal streaming loads in CSR count/fill -- R4 showed fill's
// 101MB WRITE_SIZE (16x amp) persists because streaming dst/src reads evict
// partially-filled scatter lines from L2; nt loads stop the pollution.
// (b) PvT: tiny CSR (50K nnz, avg 1/row) + fused gather+log_softmax writing
// each out row once (kills pvt_scatter atomics, memset, log_softmax kernel).
// ---------------------------------------------------------------------------

#define F_DIM 256   // F_IN == H == 256
#define C_DIM 40
#define NPART 8

typedef _Float16 half8 __attribute__((ext_vector_type(8)));
typedef float    f32x4 __attribute__((ext_vector_type(4)));

// --- convert + transpose weight: w[k][n] fp32 -> wt[n][k] fp16  (256x256)
__global__ __launch_bounds__(256) void cvt_wT(
    const float* __restrict__ w, _Float16* __restrict__ wt)
{
    const int n = threadIdx.x;
    const int k = blockIdx.x;
    wt[n * 256 + k] = (_Float16)w[k * 256 + n];
}

// --- convert + transpose + pad FC weight: wfc[k][40] fp32 -> wt[48][256] fp16
__global__ __launch_bounds__(48) void cvt_wfc(
    const float* __restrict__ wfc, _Float16* __restrict__ wt)
{
    const int n = threadIdx.x;   // 0..47
    const int k = blockIdx.x;    // 0..255
    wt[n * 256 + k] = (n < C_DIM) ? (_Float16)wfc[k * C_DIM + n] : (_Float16)0.f;
}

// --- MFMA fp16 GEMM: out[M x 256] = f16(relu(A[M x 256] @ Wt^T + bias))
//     A read straight into MFMA A-frags (no LDS); B tile staged once.
template <bool AF32>
__global__ __launch_bounds__(256, 2) void gemm_f16(
    const void* __restrict__ Av, const _Float16* __restrict__ Wt,
    const float* __restrict__ bias, _Float16* __restrict__ out, int M)
{
    constexpr int K = 256;
    constexpr int LDB = 264;                // 132 words ≡ 4 mod 32: conflict-free
    __shared__ _Float16 Bs[128 * LDB];

    const int tid  = threadIdx.x;
    const int wave = tid >> 6;
    const int lane = tid & 63;
    const int quad = lane >> 4;
    const int l16  = lane & 15;
    const int row0 = blockIdx.x * 128;
    const int col0 = blockIdx.y * 128;

    #pragma unroll
    for (int c = 0; c < 16; ++c) {
        const int idx = c * 256 + tid;
        const int n   = idx >> 5;
        const int ko  = (idx & 31) * 8;
        *(half8*)&Bs[n * LDB + ko] = *(const half8*)(Wt + (size_t)(col0 + n) * K + ko);
    }
    __syncthreads();

    const int gr0 = min(row0 + wave * 32 + l16,      M - 1);
    const int gr1 = min(row0 + wave * 32 + 16 + l16, M - 1);

    f32x4 acc[2][8] = {};

    for (int k0 = 0; k0 < K; k0 += 32) {
        half8 af[2];
        if constexpr (AF32) {
            const float* A = (const float*)Av;
            #pragma unroll
            for (int mi = 0; mi < 2; ++mi) {
                const int gr = mi ? gr1 : gr0;
                const float4 u0 = *(const float4*)(A + (size_t)gr * K + k0 + quad * 8);
                const float4 u1 = *(const float4*)(A + (size_t)gr * K + k0 + quad * 8 + 4);
                af[mi][0] = (_Float16)u0.x; af[mi][1] = (_Float16)u0.y;
                af[mi][2] = (_Float16)u0.z; af[mi][3] = (_Float16)u0.w;
                af[mi][4] = (_Float16)u1.x; af[mi][5] = (_Float16)u1.y;
                af[mi][6] = (_Float16)u1.z; af[mi][7] = (_Float16)u1.w;
            }
        } else {
            const _Float16* A = (const _Float16*)Av;
            af[0] = *(const half8*)(A + (size_t)gr0 * K + k0 + quad * 8);
            af[1] = *(const half8*)(A + (size_t)gr1 * K + k0 + quad * 8);
        }
        #pragma unroll
        for (int ni = 0; ni < 8; ++ni) {
            const half8 bf = *(const half8*)&Bs[(ni * 16 + l16) * LDB + k0 + quad * 8];
            acc[0][ni] = __builtin_amdgcn_mfma_f32_16x16x32_f16(af[0], bf, acc[0][ni], 0, 0, 0);
            acc[1][ni] = __builtin_amdgcn_mfma_f32_16x16x32_f16(af[1], bf, acc[1][ni], 0, 0, 0);
        }
    }

    // epilogue: C/D layout col=lane&15, row=quad*4+reg
    #pragma unroll
    for (int ni = 0; ni < 8; ++ni) {
        const int col = col0 + ni * 16 + l16;
        const float b = bias[col];
        #pragma unroll
        for (int mi = 0; mi < 2; ++mi) {
            #pragma unroll
            for (int r = 0; r < 4; ++r) {
                const int grow = row0 + wave * 32 + mi * 16 + quad * 4 + r;
                if (grow < M) {
                    const float v = fmaxf(acc[mi][ni][r] + b, 0.f);
                    out[(size_t)grow * K + col] = (_Float16)v;
                }
            }
        }
    }
}

// --- MFMA FC: logits[M x 40] = h[M x 256] @ wfcT^T + bfc  (no relu)
__global__ __launch_bounds__(256, 2) void fc_mfma(
    const _Float16* __restrict__ h, const _Float16* __restrict__ WfcT,
    const float* __restrict__ bfc, float* __restrict__ logits, int M)
{
    constexpr int K = 256;
    constexpr int LDB = 264;
    __shared__ _Float16 Bs[48 * LDB];

    const int tid  = threadIdx.x;
    const int wave = tid >> 6;
    const int lane = tid & 63;
    const int quad = lane >> 4;
    const int l16  = lane & 15;
    const int row0 = blockIdx.x * 128;

    #pragma unroll
    for (int c = 0; c < 6; ++c) {
        const int idx = c * 256 + tid;
        const int n   = idx >> 5;
        const int ko  = (idx & 31) * 8;
        *(half8*)&Bs[n * LDB + ko] = *(const half8*)(WfcT + (size_t)n * K + ko);
    }
    __syncthreads();

    const int gr0 = min(row0 + wave * 32 + l16,      M - 1);
    const int gr1 = min(row0 + wave * 32 + 16 + l16, M - 1);

    f32x4 acc[2][3] = {};

    for (int k0 = 0; k0 < K; k0 += 32) {
        half8 af[2];
        af[0] = *(const half8*)(h + (size_t)gr0 * K + k0 + quad * 8);
        af[1] = *(const half8*)(h + (size_t)gr1 * K + k0 + quad * 8);
        #pragma unroll
        for (int ni = 0; ni < 3; ++ni) {
            const half8 bf = *(const half8*)&Bs[(ni * 16 + l16) * LDB + k0 + quad * 8];
            acc[0][ni] = __builtin_amdgcn_mfma_f32_16x16x32_f16(af[0], bf, acc[0][ni], 0, 0, 0);
            acc[1][ni] = __builtin_amdgcn_mfma_f32_16x16x32_f16(af[1], bf, acc[1][ni], 0, 0, 0);
        }
    }

    #pragma unroll
    for (int ni = 0; ni < 3; ++ni) {
        const int col = ni * 16 + l16;
        if (col >= C_DIM) continue;
        const float b = bfc[col];
        #pragma unroll
        for (int mi = 0; mi < 2; ++mi) {
            #pragma unroll
            for (int r = 0; r < 4; ++r) {
                const int grow = row0 + wave * 32 + mi * 16 + quad * 4 + r;
                if (grow < M)
                    logits[(size_t)grow * C_DIM + col] = acc[mi][ni][r] + b;
            }
        }
    }
}

// --- CSR build step 1: degree histogram, XCD-partitioned, nt streaming reads
__global__ __launch_bounds__(256) void count_deg_part(
    const int* __restrict__ dst, int* __restrict__ deg, int E, int partSize)
{
    const int part  = blockIdx.x & (NPART - 1);
    const int chunk = blockIdx.x >> 3;
    const int i = chunk * 256 + threadIdx.x;
    if (i >= E) return;
    const int d = __builtin_nontemporal_load(&dst[i]);
    const int lo = part * partSize;
    if (d < lo || d >= lo + partSize) return;
    atomicAdd(&deg[d], 1);
}

// --- simple histogram (for tiny PvT row counts)
__global__ __launch_bounds__(256) void count_simple(
    const int* __restrict__ idx, int* __restrict__ deg, int n)
{
    const int i = blockIdx.x * 256 + threadIdx.x;
    if (i < n) atomicAdd(&deg[__builtin_nontemporal_load(&idx[i])], 1);
}

// --- CSR build step 2: exclusive scan, int4/thread; writes rowptr AND cursor
__global__ __launch_bounds__(1024) void scan_deg4(
    const int* __restrict__ deg, int* __restrict__ rowptr,
    int* __restrict__ cursor, int N)
{
    __shared__ int waveSums[16];
    __shared__ int carrySh;
    const int tid  = threadIdx.x;
    const int lane = tid & 63;
    const int wid  = tid >> 6;
    const int N4 = N >> 2;                  // N divisible by 4
    if (tid == 0) carrySh = 0;
    __syncthreads();
    for (int base = 0; base < N4; base += 1024) {
        const int i4 = base + tid;
        int4 v = make_int4(0, 0, 0, 0);
        if (i4 < N4) v = ((const int4*)deg)[i4];
        const int tsum = v.x + v.y + v.z + v.w;
        int s = tsum;
        #pragma unroll
        for (int off = 1; off < 64; off <<= 1) {
            const int t = __shfl_up(s, off, 64);
            if (lane >= off) s += t;
        }
        if (lane == 63) waveSums[wid] = s;
        __syncthreads();
        if (wid == 0) {
            const int ws = (lane < 16) ? waveSums[lane] : 0;
            int ss = ws;
            #pragma unroll
            for (int off = 1; off < 16; off <<= 1) {
                const int t = __shfl_up(ss, off, 64);
                if (lane >= off) ss += t;
            }
            if (lane < 16) waveSums[lane] = ss - ws;   // exclusive
        }
        __syncthreads();
        const int carry = carrySh;
        if (i4 < N4) {
            const int e0 = carry + waveSums[wid] + (s - tsum);
            int4 o;
            o.x = e0;
            o.y = e0 + v.x;
            o.z = e0 + v.x + v.y;
            o.w = e0 + v.x + v.y + v.z;
            ((int4*)rowptr)[i4] = o;
            ((int4*)cursor)[i4] = o;
        }
        __syncthreads();
        if (tid == 1023) carrySh = carry + waveSums[15] + s;
        __syncthreads();
    }
    if (tid == 0) rowptr[N] = carrySh;
}

// --- CSR build step 3: scatter src ids, XCD-partitioned, nt streaming reads
__global__ __launch_bounds__(256) void fill_csr_part(
    const int* __restrict__ src, const int* __restrict__ dst,
    int* __restrict__ cursor, int* __restrict__ csr_src, int E, int partSize)
{
    const int part  = blockIdx.x & (NPART - 1);
    const int chunk = blockIdx.x >> 3;
    const int i = chunk * 256 + threadIdx.x;
    if (i >= E) return;
    const int d = __builtin_nontemporal_load(&dst[i]);
    const int lo = part * partSize;
    if (d < lo || d >= lo + partSize) return;
    const int s = __builtin_nontemporal_load(&src[i]);
    const int pos = atomicAdd(&cursor[d], 1);
    csr_src[pos] = s;
}

// --- PvT CSR fill: scatter (col, val) pairs by row cursor (tiny: 50K)
__global__ __launch_bounds__(256) void fill_pvt(
    const int* __restrict__ prow, const int* __restrict__ pcol,
    const float* __restrict__ pval, int* __restrict__ cursor,
    int* __restrict__ colS, float* __restrict__ valS, int nnz)
{
    const int i = blockIdx.x * 256 + threadIdx.x;
    if (i >= nnz) return;
    const int pos = atomicAdd(&cursor[prow[i]], 1);
    colS[pos] = pcol[i];
    valS[pos] = pval[i];
}

// --- conv aggregate: h[row] = f16(relu(msg[row] + sum_{in-edges} msg[src]))
//     2 rows per wave (32 lanes x half8 each); edge loop unrolled x8.
__global__ __launch_bounds__(256) void csr_gather_f16(
    const _Float16* __restrict__ msg, const int* __restrict__ rowptr,
    const int* __restrict__ csr_src, _Float16* __restrict__ h, int N)
{
    const int tid  = threadIdx.x;
    const int wave = tid >> 6;
    const int lane = tid & 63;
    const int g    = lane >> 5;              // row within wave (0/1)
    const int rl   = lane & 31;              // lane within row-group
    const int gsrc = lane & 32;              // shuffle base of this group
    const int row  = (blockIdx.x * 4 + wave) * 2 + g;
    if (row >= N) return;

    const int beg = rowptr[row];
    const int end = rowptr[row + 1];
    const size_t fofs = (size_t)rl * 8;

    const half8 self = *(const half8*)(msg + (size_t)row * F_DIM + fofs);
    float a[8];
    #pragma unroll
    for (int i = 0; i < 8; ++i) a[i] = (float)self[i];

    for (int e0 = beg; e0 < end; e0 += 32) {
        const int n  = min(32, end - e0);
        const int sv = (e0 + rl < end) ? csr_src[e0 + rl] : 0;
        int j = 0;
        for (; j + 8 <= n; j += 8) {
            int s[8];
            #pragma unroll
            for (int u = 0; u < 8; ++u) s[u] = __shfl(sv, gsrc + j + u, 64);
            half8 v[8];
            #pragma unroll
            for (int u = 0; u < 8; ++u)
                v[u] = *(const half8*)(msg + (size_t)s[u] * F_DIM + fofs);
            #pragma unroll
            for (int u = 0; u < 8; ++u)
                #pragma unroll
                for (int i = 0; i < 8; ++i) a[i] += (float)v[u][i];
        }
        for (; j < n; ++j) {
            const int s = __shfl(sv, gsrc + j, 64);
            const half8 v = *(const half8*)(msg + (size_t)s * F_DIM + fofs);
            #pragma unroll
            for (int i = 0; i < 8; ++i) a[i] += (float)v[i];
        }
    }

    half8 o;
    #pragma unroll
    for (int i = 0; i < 8; ++i) o[i] = (_Float16)fmaxf(a[i], 0.f);
    *(half8*)(h + (size_t)row * F_DIM + fofs) = o;
}

// --- fused PvT gather + log_softmax: one wave per out row.
//     out[r][c] = logsoftmax_c( sum_e valS[e]*logits[colS[e]][c] )
__global__ __launch_bounds__(256) void pvt_softmax(
    const float* __restrict__ logits, const int* __restrict__ prowptr,
    const int* __restrict__ colS, const float* __restrict__ valS,
    float* __restrict__ out, int N)
{
    const int row  = (blockIdx.x * 256 + threadIdx.x) >> 6;
    const int lane = threadIdx.x & 63;
    if (row >= N) return;
    const int beg = prowptr[row];
    const int end = prowptr[row + 1];
    float acc = 0.f;
    if (lane < C_DIM) {
        for (int e = beg; e < end; ++e) {
            const int   c = colS[e];
            const float v = valS[e];
            acc += v * logits[(size_t)c * C_DIM + lane];
        }
    }
    const float v = (lane < C_DIM) ? acc : -INFINITY;
    float m = v;
    #pragma unroll
    for (int off = 32; off >= 1; off >>= 1)
        m = fmaxf(m, __shfl_xor(m, off, 64));
    float e = (lane < C_DIM) ? expf(v - m) : 0.f;
    float s = e;
    #pragma unroll
    for (int off = 32; off >= 1; off >>= 1)
        s += __shfl_xor(s, off, 64);
    if (lane < C_DIM)
        out[(size_t)row * C_DIM + lane] = v - m - logf(s);
}

extern "C" void kernel_launch(void* const* d_in, const int* in_sizes, int n_in,
                              void* d_out, int out_size, void* d_ws, size_t ws_size,
                              hipStream_t stream)
{
    const float* x        = (const float*)d_in[0];
    const int*   edge_src = (const int*)d_in[1];
    const int*   edge_dst = (const int*)d_in[2];
    const int*   pvt_row  = (const int*)d_in[3];
    const int*   pvt_col  = (const int*)d_in[4];
    const float* pvt_val  = (const float*)d_in[5];
    const float* w1       = (const float*)d_in[6];
    const float* b1       = (const float*)d_in[7];
    const float* w2       = (const float*)d_in[8];
    const float* b2       = (const float*)d_in[9];
    const float* wfc      = (const float*)d_in[10];
    const float* bfc      = (const float*)d_in[11];

    const int N   = in_sizes[0] / F_DIM;   // 50000
    const int E   = in_sizes[1];           // 1600000
    const int NNZ = in_sizes[3];           // 50000

    float* out = (float*)d_out;

    // workspace layout
    const size_t nodeElems = (size_t)N * F_DIM;
    _Float16* w1t     = (_Float16*)d_ws;              // 256*256 fp16
    _Float16* w2t     = w1t + 65536;                  // 256*256 fp16
    _Float16* wfcT    = w2t + 65536;                  // 48*256 fp16
    _Float16* bufM    = wfcT + 48 * 256;              // msg, N*256 fp16
    _Float16* bufH    = bufM + nodeElems;             // h,   N*256 fp16
    float*    logits  = (float*)(bufH + nodeElems);   // N x 40 f32
    int*      deg     = (int*)(logits + (size_t)N * C_DIM);
    int*      rowptr  = deg + N;                      // N+1
    int*      cursor  = rowptr + N + 4;               // N
    int*      csr_src = cursor + N + 4;               // E
    int*      pdeg    = csr_src + E;                  // N
    int*      prowptr = pdeg + N;                     // N+1
    int*      pcursor = prowptr + N + 4;              // N
    int*      colS    = pcursor + N + 4;              // NNZ
    float*    valS    = (float*)(colS + NNZ);         // NNZ

    const int partSize = (N + NPART - 1) / NPART;

    const dim3 gemmGrid((N + 127) / 128, 2);
    const int fcBlocks    = (N + 127) / 128;
    const int ePartBlocks = ((E + 255) / 256) * NPART;
    const int rowBlocks   = (N + 3) / 4;
    const int gatherBlocks= (N + 7) / 8;              // 8 rows per block
    const int nnzBlocks   = (NNZ + 255) / 256;

    // === prep: weight conversions ===
    cvt_wT<<<256, 256, 0, stream>>>(w1, w1t);
    cvt_wT<<<256, 256, 0, stream>>>(w2, w2t);
    cvt_wfc<<<256, 48, 0, stream>>>(wfc, wfcT);

    // === edge CSR build (XCD-partitioned, nt streaming) ===
    hipMemsetAsync(deg, 0, (size_t)N * sizeof(int), stream);
    count_deg_part<<<ePartBlocks, 256, 0, stream>>>(edge_dst, deg, E, partSize);
    scan_deg4<<<1, 1024, 0, stream>>>(deg, rowptr, cursor, N);
    fill_csr_part<<<ePartBlocks, 256, 0, stream>>>(edge_src, edge_dst, cursor,
                                                   csr_src, E, partSize);

    // === PvT CSR build (tiny) ===
    hipMemsetAsync(pdeg, 0, (size_t)N * sizeof(int), stream);
    count_simple<<<nnzBlocks, 256, 0, stream>>>(pvt_row, pdeg, NNZ);
    scan_deg4<<<1, 1024, 0, stream>>>(pdeg, prowptr, pcursor, N);
    fill_pvt<<<nnzBlocks, 256, 0, stream>>>(pvt_row, pvt_col, pvt_val, pcursor,
                                            colS, valS, NNZ);

    // === layer 1 (A = fp32 x, converted inline) ===
    gemm_f16<true><<<gemmGrid, 256, 0, stream>>>(x, w1t, b1, bufM, N);
    csr_gather_f16<<<gatherBlocks, 256, 0, stream>>>(bufM, rowptr, csr_src, bufH, N);

    // === layer 2 ===
    gemm_f16<false><<<gemmGrid, 256, 0, stream>>>(bufH, w2t, b2, bufM, N);
    csr_gather_f16<<<gatherBlocks, 256, 0, stream>>>(bufM, rowptr, csr_src, bufH, N);

    // === FC (MFMA) ===
    fc_mfma<<<fcBlocks, 256, 0, stream>>>(bufH, wfcT, bfc, logits, N);

    // === fused PvT + log_softmax ===
    pvt_softmax<<<rowBlocks, 256, 0, stream>>>(logits, prowptr, colS, valS, out, N);
}

// Round 9
// 505.217 us; speedup vs baseline: 1.2054x; 1.2054x over previous
//
#include <hip/hip_runtime.h>
#include <hip/hip_bf16.h>
#include <math.h>

// ---------------------------------------------------------------------------
// MPNN node classifier.
// R8: revert R7 (nt loads + pvt-CSR regressed). Replace atomic CSR build
// (count 1.6M global atomics + fill w/ 16x write amp, ~180-200us) with a
// bucket-sort build: LDS histograms + coalesced run emission + per-bucket
// (single-XCD-owned) node scatter. Packed edge = (src<<8)|(dst&255).
// ---------------------------------------------------------------------------

#define F_DIM 256   // F_IN == H == 256
#define C_DIM 40
#define NBUCK 256   // coarse buckets: dst >> 8
#define NB    256   // scatter blocks (chunks)
#define MAXCHUNK 6400

typedef _Float16 half8 __attribute__((ext_vector_type(8)));
typedef float    f32x4 __attribute__((ext_vector_type(4)));

// --- convert + transpose weight: w[k][n] fp32 -> wt[n][k] fp16  (256x256)
__global__ __launch_bounds__(256) void cvt_wT(
    const float* __restrict__ w, _Float16* __restrict__ wt)
{
    const int n = threadIdx.x;
    const int k = blockIdx.x;
    wt[n * 256 + k] = (_Float16)w[k * 256 + n];
}

// --- convert + transpose + pad FC weight: wfc[k][40] fp32 -> wt[48][256] fp16
__global__ __launch_bounds__(48) void cvt_wfc(
    const float* __restrict__ wfc, _Float16* __restrict__ wt)
{
    const int n = threadIdx.x;   // 0..47
    const int k = blockIdx.x;    // 0..255
    wt[n * 256 + k] = (n < C_DIM) ? (_Float16)wfc[k * C_DIM + n] : (_Float16)0.f;
}

// --- MFMA fp16 GEMM: out[M x 256] = f16(relu(A[M x 256] @ Wt^T + bias))
template <bool AF32>
__global__ __launch_bounds__(256, 2) void gemm_f16(
    const void* __restrict__ Av, const _Float16* __restrict__ Wt,
    const float* __restrict__ bias, _Float16* __restrict__ out, int M)
{
    constexpr int K = 256;
    constexpr int LDB = 264;                // 132 words ≡ 4 mod 32: conflict-free
    __shared__ _Float16 Bs[128 * LDB];

    const int tid  = threadIdx.x;
    const int wave = tid >> 6;
    const int lane = tid & 63;
    const int quad = lane >> 4;
    const int l16  = lane & 15;
    const int row0 = blockIdx.x * 128;
    const int col0 = blockIdx.y * 128;

    #pragma unroll
    for (int c = 0; c < 16; ++c) {
        const int idx = c * 256 + tid;
        const int n   = idx >> 5;
        const int ko  = (idx & 31) * 8;
        *(half8*)&Bs[n * LDB + ko] = *(const half8*)(Wt + (size_t)(col0 + n) * K + ko);
    }
    __syncthreads();

    const int gr0 = min(row0 + wave * 32 + l16,      M - 1);
    const int gr1 = min(row0 + wave * 32 + 16 + l16, M - 1);

    f32x4 acc[2][8] = {};

    for (int k0 = 0; k0 < K; k0 += 32) {
        half8 af[2];
        if constexpr (AF32) {
            const float* A = (const float*)Av;
            #pragma unroll
            for (int mi = 0; mi < 2; ++mi) {
                const int gr = mi ? gr1 : gr0;
                const float4 u0 = *(const float4*)(A + (size_t)gr * K + k0 + quad * 8);
                const float4 u1 = *(const float4*)(A + (size_t)gr * K + k0 + quad * 8 + 4);
                af[mi][0] = (_Float16)u0.x; af[mi][1] = (_Float16)u0.y;
                af[mi][2] = (_Float16)u0.z; af[mi][3] = (_Float16)u0.w;
                af[mi][4] = (_Float16)u1.x; af[mi][5] = (_Float16)u1.y;
                af[mi][6] = (_Float16)u1.z; af[mi][7] = (_Float16)u1.w;
            }
        } else {
            const _Float16* A = (const _Float16*)Av;
            af[0] = *(const half8*)(A + (size_t)gr0 * K + k0 + quad * 8);
            af[1] = *(const half8*)(A + (size_t)gr1 * K + k0 + quad * 8);
        }
        #pragma unroll
        for (int ni = 0; ni < 8; ++ni) {
            const half8 bf = *(const half8*)&Bs[(ni * 16 + l16) * LDB + k0 + quad * 8];
            acc[0][ni] = __builtin_amdgcn_mfma_f32_16x16x32_f16(af[0], bf, acc[0][ni], 0, 0, 0);
            acc[1][ni] = __builtin_amdgcn_mfma_f32_16x16x32_f16(af[1], bf, acc[1][ni], 0, 0, 0);
        }
    }

    // epilogue: C/D layout col=lane&15, row=quad*4+reg
    #pragma unroll
    for (int ni = 0; ni < 8; ++ni) {
        const int col = col0 + ni * 16 + l16;
        const float b = bias[col];
        #pragma unroll
        for (int mi = 0; mi < 2; ++mi) {
            #pragma unroll
            for (int r = 0; r < 4; ++r) {
                const int grow = row0 + wave * 32 + mi * 16 + quad * 4 + r;
                if (grow < M) {
                    const float v = fmaxf(acc[mi][ni][r] + b, 0.f);
                    out[(size_t)grow * K + col] = (_Float16)v;
                }
            }
        }
    }
}

// --- MFMA FC: logits[M x 40] = h[M x 256] @ wfcT^T + bfc  (no relu)
__global__ __launch_bounds__(256, 2) void fc_mfma(
    const _Float16* __restrict__ h, const _Float16* __restrict__ WfcT,
    const float* __restrict__ bfc, float* __restrict__ logits, int M)
{
    constexpr int K = 256;
    constexpr int LDB = 264;
    __shared__ _Float16 Bs[48 * LDB];

    const int tid  = threadIdx.x;
    const int wave = tid >> 6;
    const int lane = tid & 63;
    const int quad = lane >> 4;
    const int l16  = lane & 15;
    const int row0 = blockIdx.x * 128;

    #pragma unroll
    for (int c = 0; c < 6; ++c) {
        const int idx = c * 256 + tid;
        const int n   = idx >> 5;
        const int ko  = (idx & 31) * 8;
        *(half8*)&Bs[n * LDB + ko] = *(const half8*)(WfcT + (size_t)n * K + ko);
    }
    __syncthreads();

    const int gr0 = min(row0 + wave * 32 + l16,      M - 1);
    const int gr1 = min(row0 + wave * 32 + 16 + l16, M - 1);

    f32x4 acc[2][3] = {};

    for (int k0 = 0; k0 < K; k0 += 32) {
        half8 af[2];
        af[0] = *(const half8*)(h + (size_t)gr0 * K + k0 + quad * 8);
        af[1] = *(const half8*)(h + (size_t)gr1 * K + k0 + quad * 8);
        #pragma unroll
        for (int ni = 0; ni < 3; ++ni) {
            const half8 bf = *(const half8*)&Bs[(ni * 16 + l16) * LDB + k0 + quad * 8];
            acc[0][ni] = __builtin_amdgcn_mfma_f32_16x16x32_f16(af[0], bf, acc[0][ni], 0, 0, 0);
            acc[1][ni] = __builtin_amdgcn_mfma_f32_16x16x32_f16(af[1], bf, acc[1][ni], 0, 0, 0);
        }
    }

    #pragma unroll
    for (int ni = 0; ni < 3; ++ni) {
        const int col = ni * 16 + l16;
        if (col >= C_DIM) continue;
        const float b = bfc[col];
        #pragma unroll
        for (int mi = 0; mi < 2; ++mi) {
            #pragma unroll
            for (int r = 0; r < 4; ++r) {
                const int grow = row0 + wave * 32 + mi * 16 + quad * 4 + r;
                if (grow < M)
                    logits[(size_t)grow * C_DIM + col] = acc[mi][ni][r] + b;
            }
        }
    }
}

// --- bucket CSR step 1: per-chunk LDS histogram of coarse buckets (dst>>8)
__global__ __launch_bounds__(256) void bucket_count(
    const int* __restrict__ dst, int* __restrict__ cntMat, int E, int chunk)
{
    __shared__ int lcnt[NBUCK];
    const int tid = threadIdx.x;
    const int k   = blockIdx.x;
    lcnt[tid] = 0;
    __syncthreads();
    const int e0 = k * chunk;
    const int e1 = min(e0 + chunk, E);
    for (int i = e0 + tid; i < e1; i += 256)
        atomicAdd(&lcnt[dst[i] >> 8], 1);
    __syncthreads();
    cntMat[tid * NB + k] = lcnt[tid];
}

// --- exclusive scan, int4/thread (single workgroup); writes rowptr AND cursor
__global__ __launch_bounds__(1024) void scan_deg4(
    const int* __restrict__ deg, int* __restrict__ rowptr,
    int* __restrict__ cursor, int N)
{
    __shared__ int waveSums[16];
    __shared__ int carrySh;
    const int tid  = threadIdx.x;
    const int lane = tid & 63;
    const int wid  = tid >> 6;
    const int N4 = N >> 2;                  // N divisible by 4
    if (tid == 0) carrySh = 0;
    __syncthreads();
    for (int base = 0; base < N4; base += 1024) {
        const int i4 = base + tid;
        int4 v = make_int4(0, 0, 0, 0);
        if (i4 < N4) v = ((const int4*)deg)[i4];
        const int tsum = v.x + v.y + v.z + v.w;
        int s = tsum;
        #pragma unroll
        for (int off = 1; off < 64; off <<= 1) {
            const int t = __shfl_up(s, off, 64);
            if (lane >= off) s += t;
        }
        if (lane == 63) waveSums[wid] = s;
        __syncthreads();
        if (wid == 0) {
            const int ws = (lane < 16) ? waveSums[lane] : 0;
            int ss = ws;
            #pragma unroll
            for (int off = 1; off < 16; off <<= 1) {
                const int t = __shfl_up(ss, off, 64);
                if (lane >= off) ss += t;
            }
            if (lane < 16) waveSums[lane] = ss - ws;   // exclusive
        }
        __syncthreads();
        const int carry = carrySh;
        if (i4 < N4) {
            const int e0 = carry + waveSums[wid] + (s - tsum);
            int4 o;
            o.x = e0;
            o.y = e0 + v.x;
            o.z = e0 + v.x + v.y;
            o.w = e0 + v.x + v.y + v.z;
            ((int4*)rowptr)[i4] = o;
            ((int4*)cursor)[i4] = o;
        }
        __syncthreads();
        if (tid == 1023) carrySh = carry + waveSums[15] + s;
        __syncthreads();
    }
    if (tid == 0) rowptr[N] = carrySh;
}

// --- bucket CSR step 3: LDS-reorder chunk by bucket, emit contiguous runs.
//     packed edge = (src<<8) | (dst&255)   (src<2^16, so fits 24 bits)
__global__ __launch_bounds__(256) void bucket_scatter(
    const int* __restrict__ src, const int* __restrict__ dst,
    const int* __restrict__ baseMat, int* __restrict__ packed, int E, int chunk)
{
    __shared__ int lcnt[NBUCK], loff[NBUCK], cursor[NBUCK], gbase[NBUCK];
    __shared__ int segSum[4];
    __shared__ int ldsOut[MAXCHUNK];
    const int tid  = threadIdx.x;
    const int wave = tid >> 6;
    const int lane = tid & 63;
    const int k    = blockIdx.x;
    const int e0 = k * chunk;
    const int e1 = min(e0 + chunk, E);

    lcnt[tid]  = 0;
    gbase[tid] = baseMat[tid * NB + k];
    __syncthreads();

    // phase 1: count buckets
    for (int i = e0 + tid; i < e1; i += 256)
        atomicAdd(&lcnt[dst[i] >> 8], 1);
    __syncthreads();

    // phase 2: exclusive scan lcnt -> loff (4 waves x 64)
    {
        const int v = lcnt[tid];
        int s = v;
        #pragma unroll
        for (int off = 1; off < 64; off <<= 1) {
            const int t = __shfl_up(s, off, 64);
            if (lane >= off) s += t;
        }
        loff[tid] = s - v;
        if (lane == 63) segSum[wave] = s;
    }
    __syncthreads();
    if (tid == 0) {
        int c = 0;
        #pragma unroll
        for (int w = 0; w < 4; ++w) { const int t = segSum[w]; segSum[w] = c; c += t; }
    }
    __syncthreads();
    loff[tid] += segSum[wave];
    cursor[tid] = 0;
    __syncthreads();

    // phase 3: re-read chunk, place packed values bucket-ordered in LDS
    for (int i = e0 + tid; i < e1; i += 256) {
        const int d = dst[i];
        const int b = d >> 8;
        const int pos = atomicAdd(&cursor[b], 1);
        ldsOut[loff[b] + pos] = (src[i] << 8) | (d & 255);
    }
    __syncthreads();

    // phase 4: emit each bucket's run contiguously (wave per bucket rr)
    for (int b = wave; b < NBUCK; b += 4) {
        const int cnt = lcnt[b];
        const int gb  = gbase[b];
        const int lb  = loff[b];
        for (int j = lane; j < cnt; j += 64)
            packed[gb + j] = ldsOut[lb + j];
    }
}

// --- bucket CSR step 4: per-bucket node histogram -> rowptr + ordered csr_src
//     block b owns global range [gbeg,gend) (~32KB, single-XCD resident)
__global__ __launch_bounds__(256) void bucket_to_csr(
    const int* __restrict__ packed, const int* __restrict__ baseMat,
    int* __restrict__ rowptr, int* __restrict__ csr_src, int N)
{
    __shared__ int lcnt[NBUCK], loff[NBUCK], cursor[NBUCK];
    __shared__ int segSum[4];
    const int tid  = threadIdx.x;
    const int wave = tid >> 6;
    const int lane = tid & 63;
    const int b    = blockIdx.x;
    const int gbeg = baseMat[b * NB];
    const int gend = baseMat[(b + 1) * NB];

    const int nodeBase = b * NBUCK;
    if (nodeBase > N) return;               // bucket beyond node range

    lcnt[tid] = 0;
    __syncthreads();

    // phase 1: histogram of low-8 node ids
    for (int e = gbeg + tid; e < gend; e += 256)
        atomicAdd(&lcnt[packed[e] & 255], 1);
    __syncthreads();

    // phase 2: exclusive scan lcnt -> loff
    {
        const int v = lcnt[tid];
        int s = v;
        #pragma unroll
        for (int off = 1; off < 64; off <<= 1) {
            const int t = __shfl_up(s, off, 64);
            if (lane >= off) s += t;
        }
        loff[tid] = s - v;
        if (lane == 63) segSum[wave] = s;
    }
    __syncthreads();
    if (tid == 0) {
        int c = 0;
        #pragma unroll
        for (int w = 0; w < 4; ++w) { const int t = segSum[w]; segSum[w] = c; c += t; }
    }
    __syncthreads();
    loff[tid] += segSum[wave];
    cursor[tid] = 0;
    __syncthreads();

    // phase 3: rowptr for owned nodes (p == N handled by last valid bucket)
    if (nodeBase + tid <= N)
        rowptr[nodeBase + tid] = gbeg + loff[tid];
    __syncthreads();

    // phase 4: scatter src ids ordered by node (block-owned region)
    for (int e = gbeg + tid; e < gend; e += 256) {
        const int p = packed[e];
        const int node = p & 255;
        const int pos = atomicAdd(&cursor[node], 1);
        csr_src[gbeg + loff[node] + pos] = p >> 8;
    }
}

// --- conv aggregate: h[row] = f16(relu(msg[row] + sum_{in-edges} msg[src]))
//     2 rows per wave (32 lanes x half8 each); edge loop unrolled x8.
__global__ __launch_bounds__(256) void csr_gather_f16(
    const _Float16* __restrict__ msg, const int* __restrict__ rowptr,
    const int* __restrict__ csr_src, _Float16* __restrict__ h, int N)
{
    const int tid  = threadIdx.x;
    const int wave = tid >> 6;
    const int lane = tid & 63;
    const int g    = lane >> 5;              // row within wave (0/1)
    const int rl   = lane & 31;              // lane within row-group
    const int gsrc = lane & 32;              // shuffle base of this group
    const int row  = (blockIdx.x * 4 + wave) * 2 + g;
    if (row >= N) return;

    const int beg = rowptr[row];
    const int end = rowptr[row + 1];
    const size_t fofs = (size_t)rl * 8;

    const half8 self = *(const half8*)(msg + (size_t)row * F_DIM + fofs);
    float a[8];
    #pragma unroll
    for (int i = 0; i < 8; ++i) a[i] = (float)self[i];

    for (int e0 = beg; e0 < end; e0 += 32) {
        const int n  = min(32, end - e0);
        const int sv = (e0 + rl < end) ? csr_src[e0 + rl] : 0;
        int j = 0;
        for (; j + 8 <= n; j += 8) {
            int s[8];
            #pragma unroll
            for (int u = 0; u < 8; ++u) s[u] = __shfl(sv, gsrc + j + u, 64);
            half8 v[8];
            #pragma unroll
            for (int u = 0; u < 8; ++u)
                v[u] = *(const half8*)(msg + (size_t)s[u] * F_DIM + fofs);
            #pragma unroll
            for (int u = 0; u < 8; ++u)
                #pragma unroll
                for (int i = 0; i < 8; ++i) a[i] += (float)v[u][i];
        }
        for (; j < n; ++j) {
            const int s = __shfl(sv, gsrc + j, 64);
            const half8 v = *(const half8*)(msg + (size_t)s * F_DIM + fofs);
            #pragma unroll
            for (int i = 0; i < 8; ++i) a[i] += (float)v[i];
        }
    }

    half8 o;
    #pragma unroll
    for (int i = 0; i < 8; ++i) o[i] = (_Float16)fmaxf(a[i], 0.f);
    *(half8*)(h + (size_t)row * F_DIM + fofs) = o;
}

// --- sparse PvT: out[prow[i]] += pval[i] * logits[pcol[i]], wave/nnz
__global__ __launch_bounds__(256) void pvt_scatter(
    const float* __restrict__ logits, const int* __restrict__ prow,
    const int* __restrict__ pcol, const float* __restrict__ pval,
    float* __restrict__ out, int nnz)
{
    const int i    = (blockIdx.x * 256 + threadIdx.x) >> 6;
    const int lane = threadIdx.x & 63;
    if (i >= nnz || lane >= C_DIM) return;
    const int r = prow[i];
    const int c = pcol[i];
    const float v = pval[i];
    atomicAdd(out + (size_t)r * C_DIM + lane, v * logits[(size_t)c * C_DIM + lane]);
}

// --- row-wise log_softmax in place, wave/row (lanes 0..39 active)
__global__ __launch_bounds__(256) void log_softmax40(float* __restrict__ out, int M)
{
    const int row  = (blockIdx.x * 256 + threadIdx.x) >> 6;
    const int lane = threadIdx.x & 63;
    if (row >= M) return;
    const float v = (lane < C_DIM) ? out[(size_t)row * C_DIM + lane] : -INFINITY;
    float m = v;
    #pragma unroll
    for (int off = 32; off >= 1; off >>= 1)
        m = fmaxf(m, __shfl_xor(m, off, 64));
    float e = (lane < C_DIM) ? expf(v - m) : 0.f;
    float s = e;
    #pragma unroll
    for (int off = 32; off >= 1; off >>= 1)
        s += __shfl_xor(s, off, 64);
    if (lane < C_DIM)
        out[(size_t)row * C_DIM + lane] = v - m - logf(s);
}

extern "C" void kernel_launch(void* const* d_in, const int* in_sizes, int n_in,
                              void* d_out, int out_size, void* d_ws, size_t ws_size,
                              hipStream_t stream)
{
    const float* x        = (const float*)d_in[0];
    const int*   edge_src = (const int*)d_in[1];
    const int*   edge_dst = (const int*)d_in[2];
    const int*   pvt_row  = (const int*)d_in[3];
    const int*   pvt_col  = (const int*)d_in[4];
    const float* pvt_val  = (const float*)d_in[5];
    const float* w1       = (const float*)d_in[6];
    const float* b1       = (const float*)d_in[7];
    const float* w2       = (const float*)d_in[8];
    const float* b2       = (const float*)d_in[9];
    const float* wfc      = (const float*)d_in[10];
    const float* bfc      = (const float*)d_in[11];

    const int N   = in_sizes[0] / F_DIM;   // 50000
    const int E   = in_sizes[1];           // 1600000
    const int NNZ = in_sizes[3];           // 50000

    float* out = (float*)d_out;

    // workspace layout
    const size_t nodeElems = (size_t)N * F_DIM;
    _Float16* w1t     = (_Float16*)d_ws;              // 256*256 fp16
    _Float16* w2t     = w1t + 65536;                  // 256*256 fp16
    _Float16* wfcT    = w2t + 65536;                  // 48*256 fp16
    _Float16* bufM    = wfcT + 48 * 256;              // msg, N*256 fp16
    _Float16* bufH    = bufM + nodeElems;             // h,   N*256 fp16
    float*    logits  = (float*)(bufH + nodeElems);   // N x 40 f32
    int*      cntMat  = (int*)(logits + (size_t)N * C_DIM); // 65536
    int*      baseMat = cntMat + 65536;               // 65537 (+pad)
    int*      rowptr  = baseMat + 65544;              // N+1 (+pad)
    int*      csr_src = rowptr + N + 8;               // E
    int*      packed  = csr_src + E;                  // E

    const int chunk = (E + NB - 1) / NB;              // 6250, <= MAXCHUNK

    const dim3 gemmGrid((N + 127) / 128, 2);
    const int fcBlocks    = (N + 127) / 128;
    const int rowBlocks   = (N + 3) / 4;
    const int gatherBlocks= (N + 7) / 8;              // 8 rows per block
    const int nnzBlocks   = (NNZ + 3) / 4;

    // === prep: weight conversions ===
    cvt_wT<<<256, 256, 0, stream>>>(w1, w1t);
    cvt_wT<<<256, 256, 0, stream>>>(w2, w2t);
    cvt_wfc<<<256, 48, 0, stream>>>(wfc, wfcT);

    // === bucket-sort CSR build ===
    bucket_count<<<NB, 256, 0, stream>>>(edge_dst, cntMat, E, chunk);
    scan_deg4<<<1, 1024, 0, stream>>>(cntMat, baseMat, baseMat, NBUCK * NB);
    bucket_scatter<<<NB, 256, 0, stream>>>(edge_src, edge_dst, baseMat, packed, E, chunk);
    bucket_to_csr<<<NBUCK, 256, 0, stream>>>(packed, baseMat, rowptr, csr_src, N);

    // === layer 1 (A = fp32 x, converted inline) ===
    gemm_f16<true><<<gemmGrid, 256, 0, stream>>>(x, w1t, b1, bufM, N);
    csr_gather_f16<<<gatherBlocks, 256, 0, stream>>>(bufM, rowptr, csr_src, bufH, N);

    // === layer 2 ===
    gemm_f16<false><<<gemmGrid, 256, 0, stream>>>(bufH, w2t, b2, bufM, N);
    csr_gather_f16<<<gatherBlocks, 256, 0, stream>>>(bufM, rowptr, csr_src, bufH, N);

    // === FC (MFMA) ===
    fc_mfma<<<fcBlocks, 256, 0, stream>>>(bufH, wfcT, bfc, logits, N);

    // === PvT scatter into d_out, then log_softmax ===
    hipMemsetAsync(d_out, 0, (size_t)N * C_DIM * sizeof(float), stream);
    pvt_scatter<<<nnzBlocks, 256, 0, stream>>>(logits, pvt_row, pvt_col, pvt_val, out, NNZ);
    log_softmax40<<<rowBlocks, 256, 0, stream>>>(out, N);
}

// Round 10
// 502.574 us; speedup vs baseline: 1.2117x; 1.0053x over previous
//
#include <hip/hip_runtime.h>
#include <hip/hip_bf16.h>
#include <math.h>

// ---------------------------------------------------------------------------
// MPNN node classifier.
// R9: (1) bucket_scatter reads cntMat instead of re-histogramming its chunk
// (saves a 6.4MB pass); (2) 3 cvt launches -> 1; (3) gather probes 512-thread
// blocks (occupancy was 43% with no resource limiter -- if latency-bound,
// more waves help; if LLC-bound, neutral).
// ---------------------------------------------------------------------------

#define F_DIM 256   // F_IN == H == 256
#define C_DIM 40
#define NBUCK 256   // coarse buckets: dst >> 8
#define NB    256   // scatter blocks (chunks)
#define MAXCHUNK 6400

typedef _Float16 half8 __attribute__((ext_vector_type(8)));
typedef float    f32x4 __attribute__((ext_vector_type(4)));

// --- all weight conversions in one kernel.
//     y=0: w1 -> w1t[n][k]; y=1: w2 -> w2t[n][k]; y=2: wfc -> wfcT[48][256]
__global__ __launch_bounds__(256) void cvt_all(
    const float* __restrict__ w1, const float* __restrict__ w2,
    const float* __restrict__ wfc, _Float16* __restrict__ w1t,
    _Float16* __restrict__ w2t, _Float16* __restrict__ wfcT)
{
    const int n = threadIdx.x;
    const int k = blockIdx.x;
    const int y = blockIdx.y;
    if (y == 0)      w1t[n * 256 + k] = (_Float16)w1[k * 256 + n];
    else if (y == 1) w2t[n * 256 + k] = (_Float16)w2[k * 256 + n];
    else if (n < 48)
        wfcT[n * 256 + k] = (n < C_DIM) ? (_Float16)wfc[k * C_DIM + n] : (_Float16)0.f;
}

// --- MFMA fp16 GEMM: out[M x 256] = f16(relu(A[M x 256] @ Wt^T + bias))
template <bool AF32>
__global__ __launch_bounds__(256, 2) void gemm_f16(
    const void* __restrict__ Av, const _Float16* __restrict__ Wt,
    const float* __restrict__ bias, _Float16* __restrict__ out, int M)
{
    constexpr int K = 256;
    constexpr int LDB = 264;                // 132 words ≡ 4 mod 32: conflict-free
    __shared__ _Float16 Bs[128 * LDB];

    const int tid  = threadIdx.x;
    const int wave = tid >> 6;
    const int lane = tid & 63;
    const int quad = lane >> 4;
    const int l16  = lane & 15;
    const int row0 = blockIdx.x * 128;
    const int col0 = blockIdx.y * 128;

    #pragma unroll
    for (int c = 0; c < 16; ++c) {
        const int idx = c * 256 + tid;
        const int n   = idx >> 5;
        const int ko  = (idx & 31) * 8;
        *(half8*)&Bs[n * LDB + ko] = *(const half8*)(Wt + (size_t)(col0 + n) * K + ko);
    }
    __syncthreads();

    const int gr0 = min(row0 + wave * 32 + l16,      M - 1);
    const int gr1 = min(row0 + wave * 32 + 16 + l16, M - 1);

    f32x4 acc[2][8] = {};

    for (int k0 = 0; k0 < K; k0 += 32) {
        half8 af[2];
        if constexpr (AF32) {
            const float* A = (const float*)Av;
            #pragma unroll
            for (int mi = 0; mi < 2; ++mi) {
                const int gr = mi ? gr1 : gr0;
                const float4 u0 = *(const float4*)(A + (size_t)gr * K + k0 + quad * 8);
                const float4 u1 = *(const float4*)(A + (size_t)gr * K + k0 + quad * 8 + 4);
                af[mi][0] = (_Float16)u0.x; af[mi][1] = (_Float16)u0.y;
                af[mi][2] = (_Float16)u0.z; af[mi][3] = (_Float16)u0.w;
                af[mi][4] = (_Float16)u1.x; af[mi][5] = (_Float16)u1.y;
                af[mi][6] = (_Float16)u1.z; af[mi][7] = (_Float16)u1.w;
            }
        } else {
            const _Float16* A = (const _Float16*)Av;
            af[0] = *(const half8*)(A + (size_t)gr0 * K + k0 + quad * 8);
            af[1] = *(const half8*)(A + (size_t)gr1 * K + k0 + quad * 8);
        }
        #pragma unroll
        for (int ni = 0; ni < 8; ++ni) {
            const half8 bf = *(const half8*)&Bs[(ni * 16 + l16) * LDB + k0 + quad * 8];
            acc[0][ni] = __builtin_amdgcn_mfma_f32_16x16x32_f16(af[0], bf, acc[0][ni], 0, 0, 0);
            acc[1][ni] = __builtin_amdgcn_mfma_f32_16x16x32_f16(af[1], bf, acc[1][ni], 0, 0, 0);
        }
    }

    // epilogue: C/D layout col=lane&15, row=quad*4+reg
    #pragma unroll
    for (int ni = 0; ni < 8; ++ni) {
        const int col = col0 + ni * 16 + l16;
        const float b = bias[col];
        #pragma unroll
        for (int mi = 0; mi < 2; ++mi) {
            #pragma unroll
            for (int r = 0; r < 4; ++r) {
                const int grow = row0 + wave * 32 + mi * 16 + quad * 4 + r;
                if (grow < M) {
                    const float v = fmaxf(acc[mi][ni][r] + b, 0.f);
                    out[(size_t)grow * K + col] = (_Float16)v;
                }
            }
        }
    }
}

// --- MFMA FC: logits[M x 40] = h[M x 256] @ wfcT^T + bfc  (no relu)
__global__ __launch_bounds__(256, 2) void fc_mfma(
    const _Float16* __restrict__ h, const _Float16* __restrict__ WfcT,
    const float* __restrict__ bfc, float* __restrict__ logits, int M)
{
    constexpr int K = 256;
    constexpr int LDB = 264;
    __shared__ _Float16 Bs[48 * LDB];

    const int tid  = threadIdx.x;
    const int wave = tid >> 6;
    const int lane = tid & 63;
    const int quad = lane >> 4;
    const int l16  = lane & 15;
    const int row0 = blockIdx.x * 128;

    #pragma unroll
    for (int c = 0; c < 6; ++c) {
        const int idx = c * 256 + tid;
        const int n   = idx >> 5;
        const int ko  = (idx & 31) * 8;
        *(half8*)&Bs[n * LDB + ko] = *(const half8*)(WfcT + (size_t)n * K + ko);
    }
    __syncthreads();

    const int gr0 = min(row0 + wave * 32 + l16,      M - 1);
    const int gr1 = min(row0 + wave * 32 + 16 + l16, M - 1);

    f32x4 acc[2][3] = {};

    for (int k0 = 0; k0 < K; k0 += 32) {
        half8 af[2];
        af[0] = *(const half8*)(h + (size_t)gr0 * K + k0 + quad * 8);
        af[1] = *(const half8*)(h + (size_t)gr1 * K + k0 + quad * 8);
        #pragma unroll
        for (int ni = 0; ni < 3; ++ni) {
            const half8 bf = *(const half8*)&Bs[(ni * 16 + l16) * LDB + k0 + quad * 8];
            acc[0][ni] = __builtin_amdgcn_mfma_f32_16x16x32_f16(af[0], bf, acc[0][ni], 0, 0, 0);
            acc[1][ni] = __builtin_amdgcn_mfma_f32_16x16x32_f16(af[1], bf, acc[1][ni], 0, 0, 0);
        }
    }

    #pragma unroll
    for (int ni = 0; ni < 3; ++ni) {
        const int col = ni * 16 + l16;
        if (col >= C_DIM) continue;
        const float b = bfc[col];
        #pragma unroll
        for (int mi = 0; mi < 2; ++mi) {
            #pragma unroll
            for (int r = 0; r < 4; ++r) {
                const int grow = row0 + wave * 32 + mi * 16 + quad * 4 + r;
                if (grow < M)
                    logits[(size_t)grow * C_DIM + col] = acc[mi][ni][r] + b;
            }
        }
    }
}

// --- bucket CSR step 1: per-chunk LDS histogram of coarse buckets (dst>>8)
__global__ __launch_bounds__(256) void bucket_count(
    const int* __restrict__ dst, int* __restrict__ cntMat, int E, int chunk)
{
    __shared__ int lcnt[NBUCK];
    const int tid = threadIdx.x;
    const int k   = blockIdx.x;
    lcnt[tid] = 0;
    __syncthreads();
    const int e0 = k * chunk;
    const int e1 = min(e0 + chunk, E);
    for (int i = e0 + tid; i < e1; i += 256)
        atomicAdd(&lcnt[dst[i] >> 8], 1);
    __syncthreads();
    cntMat[tid * NB + k] = lcnt[tid];
}

// --- exclusive scan, int4/thread (single workgroup); writes rowptr AND cursor
__global__ __launch_bounds__(1024) void scan_deg4(
    const int* __restrict__ deg, int* __restrict__ rowptr,
    int* __restrict__ cursor, int N)
{
    __shared__ int waveSums[16];
    __shared__ int carrySh;
    const int tid  = threadIdx.x;
    const int lane = tid & 63;
    const int wid  = tid >> 6;
    const int N4 = N >> 2;                  // N divisible by 4
    if (tid == 0) carrySh = 0;
    __syncthreads();
    for (int base = 0; base < N4; base += 1024) {
        const int i4 = base + tid;
        int4 v = make_int4(0, 0, 0, 0);
        if (i4 < N4) v = ((const int4*)deg)[i4];
        const int tsum = v.x + v.y + v.z + v.w;
        int s = tsum;
        #pragma unroll
        for (int off = 1; off < 64; off <<= 1) {
            const int t = __shfl_up(s, off, 64);
            if (lane >= off) s += t;
        }
        if (lane == 63) waveSums[wid] = s;
        __syncthreads();
        if (wid == 0) {
            const int ws = (lane < 16) ? waveSums[lane] : 0;
            int ss = ws;
            #pragma unroll
            for (int off = 1; off < 16; off <<= 1) {
                const int t = __shfl_up(ss, off, 64);
                if (lane >= off) ss += t;
            }
            if (lane < 16) waveSums[lane] = ss - ws;   // exclusive
        }
        __syncthreads();
        const int carry = carrySh;
        if (i4 < N4) {
            const int e0 = carry + waveSums[wid] + (s - tsum);
            int4 o;
            o.x = e0;
            o.y = e0 + v.x;
            o.z = e0 + v.x + v.y;
            o.w = e0 + v.x + v.y + v.z;
            ((int4*)rowptr)[i4] = o;
            ((int4*)cursor)[i4] = o;
        }
        __syncthreads();
        if (tid == 1023) carrySh = carry + waveSums[15] + s;
        __syncthreads();
    }
    if (tid == 0) rowptr[N] = carrySh;
}

// --- bucket CSR step 3: LDS-reorder chunk by bucket, emit contiguous runs.
//     packed edge = (src<<8) | (dst&255). Reads counts from cntMat (no
//     recount pass).
__global__ __launch_bounds__(256) void bucket_scatter(
    const int* __restrict__ src, const int* __restrict__ dst,
    const int* __restrict__ cntMat, const int* __restrict__ baseMat,
    int* __restrict__ packed, int E, int chunk)
{
    __shared__ int lcnt[NBUCK], loff[NBUCK], cursor[NBUCK], gbase[NBUCK];
    __shared__ int segSum[4];
    __shared__ int ldsOut[MAXCHUNK];
    const int tid  = threadIdx.x;
    const int wave = tid >> 6;
    const int lane = tid & 63;
    const int k    = blockIdx.x;
    const int e0 = k * chunk;
    const int e1 = min(e0 + chunk, E);

    lcnt[tid]  = cntMat[tid * NB + k];
    gbase[tid] = baseMat[tid * NB + k];
    __syncthreads();

    // exclusive scan lcnt -> loff (4 waves x 64)
    {
        const int v = lcnt[tid];
        int s = v;
        #pragma unroll
        for (int off = 1; off < 64; off <<= 1) {
            const int t = __shfl_up(s, off, 64);
            if (lane >= off) s += t;
        }
        loff[tid] = s - v;
        if (lane == 63) segSum[wave] = s;
    }
    __syncthreads();
    if (tid == 0) {
        int c = 0;
        #pragma unroll
        for (int w = 0; w < 4; ++w) { const int t = segSum[w]; segSum[w] = c; c += t; }
    }
    __syncthreads();
    loff[tid] += segSum[wave];
    cursor[tid] = 0;
    __syncthreads();

    // read chunk, place packed values bucket-ordered in LDS
    for (int i = e0 + tid; i < e1; i += 256) {
        const int d = dst[i];
        const int b = d >> 8;
        const int pos = atomicAdd(&cursor[b], 1);
        ldsOut[loff[b] + pos] = (src[i] << 8) | (d & 255);
    }
    __syncthreads();

    // emit each bucket's run contiguously (wave per bucket rr)
    for (int b = wave; b < NBUCK; b += 4) {
        const int cnt = lcnt[b];
        const int gb  = gbase[b];
        const int lb  = loff[b];
        for (int j = lane; j < cnt; j += 64)
            packed[gb + j] = ldsOut[lb + j];
    }
}

// --- bucket CSR step 4: per-bucket node histogram -> rowptr + ordered csr_src
__global__ __launch_bounds__(256) void bucket_to_csr(
    const int* __restrict__ packed, const int* __restrict__ baseMat,
    int* __restrict__ rowptr, int* __restrict__ csr_src, int N)
{
    __shared__ int lcnt[NBUCK], loff[NBUCK], cursor[NBUCK];
    __shared__ int segSum[4];
    const int tid  = threadIdx.x;
    const int wave = tid >> 6;
    const int lane = tid & 63;
    const int b    = blockIdx.x;
    const int gbeg = baseMat[b * NB];
    const int gend = baseMat[(b + 1) * NB];

    const int nodeBase = b * NBUCK;
    if (nodeBase > N) return;               // bucket beyond node range

    lcnt[tid] = 0;
    __syncthreads();

    // histogram of low-8 node ids
    for (int e = gbeg + tid; e < gend; e += 256)
        atomicAdd(&lcnt[packed[e] & 255], 1);
    __syncthreads();

    // exclusive scan lcnt -> loff
    {
        const int v = lcnt[tid];
        int s = v;
        #pragma unroll
        for (int off = 1; off < 64; off <<= 1) {
            const int t = __shfl_up(s, off, 64);
            if (lane >= off) s += t;
        }
        loff[tid] = s - v;
        if (lane == 63) segSum[wave] = s;
    }
    __syncthreads();
    if (tid == 0) {
        int c = 0;
        #pragma unroll
        for (int w = 0; w < 4; ++w) { const int t = segSum[w]; segSum[w] = c; c += t; }
    }
    __syncthreads();
    loff[tid] += segSum[wave];
    cursor[tid] = 0;
    __syncthreads();

    // rowptr for owned nodes
    if (nodeBase + tid <= N)
        rowptr[nodeBase + tid] = gbeg + loff[tid];
    __syncthreads();

    // scatter src ids ordered by node (block-owned region)
    for (int e = gbeg + tid; e < gend; e += 256) {
        const int p = packed[e];
        const int node = p & 255;
        const int pos = atomicAdd(&cursor[node], 1);
        csr_src[gbeg + loff[node] + pos] = p >> 8;
    }
}

// --- conv aggregate: h[row] = f16(relu(msg[row] + sum_{in-edges} msg[src]))
//     512-thread blocks (8 waves, 16 rows) for more resident waves;
//     2 rows per wave (32 lanes x half8 each); edge loop unrolled x8.
__global__ __launch_bounds__(512) void csr_gather_f16(
    const _Float16* __restrict__ msg, const int* __restrict__ rowptr,
    const int* __restrict__ csr_src, _Float16* __restrict__ h, int N)
{
    const int tid  = threadIdx.x;
    const int wave = tid >> 6;
    const int lane = tid & 63;
    const int g    = lane >> 5;              // row within wave (0/1)
    const int rl   = lane & 31;              // lane within row-group
    const int gsrc = lane & 32;              // shuffle base of this group
    const int row  = (blockIdx.x * 8 + wave) * 2 + g;
    if (row >= N) return;

    const int beg = rowptr[row];
    const int end = rowptr[row + 1];
    const size_t fofs = (size_t)rl * 8;

    const half8 self = *(const half8*)(msg + (size_t)row * F_DIM + fofs);
    float a[8];
    #pragma unroll
    for (int i = 0; i < 8; ++i) a[i] = (float)self[i];

    for (int e0 = beg; e0 < end; e0 += 32) {
        const int n  = min(32, end - e0);
        const int sv = (e0 + rl < end) ? csr_src[e0 + rl] : 0;
        int j = 0;
        for (; j + 8 <= n; j += 8) {
            int s[8];
            #pragma unroll
            for (int u = 0; u < 8; ++u) s[u] = __shfl(sv, gsrc + j + u, 64);
            half8 v[8];
            #pragma unroll
            for (int u = 0; u < 8; ++u)
                v[u] = *(const half8*)(msg + (size_t)s[u] * F_DIM + fofs);
            #pragma unroll
            for (int u = 0; u < 8; ++u)
                #pragma unroll
                for (int i = 0; i < 8; ++i) a[i] += (float)v[u][i];
        }
        for (; j < n; ++j) {
            const int s = __shfl(sv, gsrc + j, 64);
            const half8 v = *(const half8*)(msg + (size_t)s * F_DIM + fofs);
            #pragma unroll
            for (int i = 0; i < 8; ++i) a[i] += (float)v[i];
        }
    }

    half8 o;
    #pragma unroll
    for (int i = 0; i < 8; ++i) o[i] = (_Float16)fmaxf(a[i], 0.f);
    *(half8*)(h + (size_t)row * F_DIM + fofs) = o;
}

// --- sparse PvT: out[prow[i]] += pval[i] * logits[pcol[i]], wave/nnz
__global__ __launch_bounds__(256) void pvt_scatter(
    const float* __restrict__ logits, const int* __restrict__ prow,
    const int* __restrict__ pcol, const float* __restrict__ pval,
    float* __restrict__ out, int nnz)
{
    const int i    = (blockIdx.x * 256 + threadIdx.x) >> 6;
    const int lane = threadIdx.x & 63;
    if (i >= nnz || lane >= C_DIM) return;
    const int r = prow[i];
    const int c = pcol[i];
    const float v = pval[i];
    atomicAdd(out + (size_t)r * C_DIM + lane, v * logits[(size_t)c * C_DIM + lane]);
}

// --- row-wise log_softmax in place, wave/row (lanes 0..39 active)
__global__ __launch_bounds__(256) void log_softmax40(float* __restrict__ out, int M)
{
    const int row  = (blockIdx.x * 256 + threadIdx.x) >> 6;
    const int lane = threadIdx.x & 63;
    if (row >= M) return;
    const float v = (lane < C_DIM) ? out[(size_t)row * C_DIM + lane] : -INFINITY;
    float m = v;
    #pragma unroll
    for (int off = 32; off >= 1; off >>= 1)
        m = fmaxf(m, __shfl_xor(m, off, 64));
    float e = (lane < C_DIM) ? expf(v - m) : 0.f;
    float s = e;
    #pragma unroll
    for (int off = 32; off >= 1; off >>= 1)
        s += __shfl_xor(s, off, 64);
    if (lane < C_DIM)
        out[(size_t)row * C_DIM + lane] = v - m - logf(s);
}

extern "C" void kernel_launch(void* const* d_in, const int* in_sizes, int n_in,
                              void* d_out, int out_size, void* d_ws, size_t ws_size,
                              hipStream_t stream)
{
    const float* x        = (const float*)d_in[0];
    const int*   edge_src = (const int*)d_in[1];
    const int*   edge_dst = (const int*)d_in[2];
    const int*   pvt_row  = (const int*)d_in[3];
    const int*   pvt_col  = (const int*)d_in[4];
    const float* pvt_val  = (const float*)d_in[5];
    const float* w1       = (const float*)d_in[6];
    const float* b1       = (const float*)d_in[7];
    const float* w2       = (const float*)d_in[8];
    const float* b2       = (const float*)d_in[9];
    const float* wfc      = (const float*)d_in[10];
    const float* bfc      = (const float*)d_in[11];

    const int N   = in_sizes[0] / F_DIM;   // 50000
    const int E   = in_sizes[1];           // 1600000
    const int NNZ = in_sizes[3];           // 50000

    float* out = (float*)d_out;

    // workspace layout
    const size_t nodeElems = (size_t)N * F_DIM;
    _Float16* w1t     = (_Float16*)d_ws;              // 256*256 fp16
    _Float16* w2t     = w1t + 65536;                  // 256*256 fp16
    _Float16* wfcT    = w2t + 65536;                  // 48*256 fp16
    _Float16* bufM    = wfcT + 48 * 256;              // msg, N*256 fp16
    _Float16* bufH    = bufM + nodeElems;             // h,   N*256 fp16
    float*    logits  = (float*)(bufH + nodeElems);   // N x 40 f32
    int*      cntMat  = (int*)(logits + (size_t)N * C_DIM); // 65536
    int*      baseMat = cntMat + 65536;               // 65537 (+pad)
    int*      rowptr  = baseMat + 65544;              // N+1 (+pad)
    int*      csr_src = rowptr + N + 8;               // E
    int*      packed  = csr_src + E;                  // E

    const int chunk = (E + NB - 1) / NB;              // 6250, <= MAXCHUNK

    const dim3 gemmGrid((N + 127) / 128, 2);
    const dim3 cvtGrid(256, 3);
    const int fcBlocks    = (N + 127) / 128;
    const int rowBlocks   = (N + 3) / 4;
    const int gatherBlocks= (N + 15) / 16;            // 16 rows per 512-blk
    const int nnzBlocks   = (NNZ + 3) / 4;

    // === prep: weight conversions (one kernel) ===
    cvt_all<<<cvtGrid, 256, 0, stream>>>(w1, w2, wfc, w1t, w2t, wfcT);

    // === bucket-sort CSR build ===
    bucket_count<<<NB, 256, 0, stream>>>(edge_dst, cntMat, E, chunk);
    scan_deg4<<<1, 1024, 0, stream>>>(cntMat, baseMat, baseMat, NBUCK * NB);
    bucket_scatter<<<NB, 256, 0, stream>>>(edge_src, edge_dst, cntMat, baseMat,
                                           packed, E, chunk);
    bucket_to_csr<<<NBUCK, 256, 0, stream>>>(packed, baseMat, rowptr, csr_src, N);

    // === layer 1 (A = fp32 x, converted inline) ===
    gemm_f16<true><<<gemmGrid, 256, 0, stream>>>(x, w1t, b1, bufM, N);
    csr_gather_f16<<<gatherBlocks, 512, 0, stream>>>(bufM, rowptr, csr_src, bufH, N);

    // === layer 2 ===
    gemm_f16<false><<<gemmGrid, 256, 0, stream>>>(bufH, w2t, b2, bufM, N);
    csr_gather_f16<<<gatherBlocks, 512, 0, stream>>>(bufM, rowptr, csr_src, bufH, N);

    // === FC (MFMA) ===
    fc_mfma<<<fcBlocks, 256, 0, stream>>>(bufH, wfcT, bfc, logits, N);

    // === PvT scatter into d_out, then log_softmax ===
    hipMemsetAsync(d_out, 0, (size_t)N * C_DIM * sizeof(float), stream);
    pvt_scatter<<<nnzBlocks, 256, 0, stream>>>(logits, pvt_row, pvt_col, pvt_val, out, NNZ);
    log_softmax40<<<rowBlocks, 256, 0, stream>>>(out, N);
}

// Round 11
// 491.341 us; speedup vs baseline: 1.2394x; 1.0229x over previous
//
#include <hip/hip_runtime.h>
#include <hip/hip_bf16.h>
#include <math.h>

// ---------------------------------------------------------------------------
// MPNN node classifier.
// R10: GEMM v3 -- wave caches its full A stripe in registers (16 x half8,
// 64 VGPRs), loops over two 128-col B halves in one 67.6KB LDS buffer:
// A global traffic halves (layer1 102->51MB, layer2 51->26MB). prep kernel
// merges weight-cvt + bucket_count. Gather untouched (LLC-bound floor,
// 107us = 355MB @ 3.6TB/s).
// ---------------------------------------------------------------------------

#define F_DIM 256   // F_IN == H == 256
#define C_DIM 40
#define NBUCK 256   // coarse buckets: dst >> 8
#define NB    256   // scatter blocks (chunks)
#define MAXCHUNK 6400

typedef _Float16 half8 __attribute__((ext_vector_type(8)));
typedef float    f32x4 __attribute__((ext_vector_type(4)));

// --- merged prep: blocks [0,NB) = bucket_count chunk histograms;
//     [NB,NB+256) w1 cvt; [NB+512) w2 cvt; [NB+768) wfc cvt+pad.
__global__ __launch_bounds__(256) void prep(
    const int* __restrict__ dst, int* __restrict__ cntMat, int E, int chunk,
    const float* __restrict__ w1, const float* __restrict__ w2,
    const float* __restrict__ wfc, _Float16* __restrict__ w1t,
    _Float16* __restrict__ w2t, _Float16* __restrict__ wfcT)
{
    __shared__ int lcnt[NBUCK];
    const int tid = threadIdx.x;
    const int bid = blockIdx.x;
    if (bid < NB) {
        lcnt[tid] = 0;
        __syncthreads();
        const int e0 = bid * chunk;
        const int e1 = min(e0 + chunk, E);
        for (int i = e0 + tid; i < e1; i += 256)
            atomicAdd(&lcnt[dst[i] >> 8], 1);
        __syncthreads();
        cntMat[tid * NB + bid] = lcnt[tid];
    } else {
        const int r = bid - NB;
        const int k = r & 255;
        const int y = r >> 8;
        const int n = tid;
        if (y == 0)      w1t[n * 256 + k] = (_Float16)w1[k * 256 + n];
        else if (y == 1) w2t[n * 256 + k] = (_Float16)w2[k * 256 + n];
        else if (n < 48)
            wfcT[n * 256 + k] = (n < C_DIM) ? (_Float16)wfc[k * C_DIM + n]
                                            : (_Float16)0.f;
    }
}

// --- MFMA fp16 GEMM v3: out[M x 256] = f16(relu(A[M x 256] @ Wt^T + bias))
//     Block = 128 rows x 256 cols, 256 threads. Wave caches its entire A
//     stripe (2 rows-of-16 x full K) in registers; B staged per 128-col half.
template <bool AF32>
__global__ __launch_bounds__(256, 2) void gemm_f16(
    const void* __restrict__ Av, const _Float16* __restrict__ Wt,
    const float* __restrict__ bias, _Float16* __restrict__ out, int M)
{
    constexpr int K = 256;
    constexpr int LDB = 264;                // 132 words ≡ 4 mod 32: conflict-free
    __shared__ _Float16 Bs[128 * LDB];

    const int tid  = threadIdx.x;
    const int wave = tid >> 6;
    const int lane = tid & 63;
    const int quad = lane >> 4;
    const int l16  = lane & 15;
    const int row0 = blockIdx.x * 128;

    const int gr0 = min(row0 + wave * 32 + l16,      M - 1);
    const int gr1 = min(row0 + wave * 32 + 16 + l16, M - 1);

    // cache full A stripe: aReg[mi][kk] covers k = kk*32 + quad*8 .. +7
    half8 aReg[2][8];
    if constexpr (AF32) {
        const float* A = (const float*)Av;
        #pragma unroll
        for (int mi = 0; mi < 2; ++mi) {
            const int gr = mi ? gr1 : gr0;
            #pragma unroll
            for (int kk = 0; kk < 8; ++kk) {
                const float4 u0 = *(const float4*)(A + (size_t)gr * K + kk * 32 + quad * 8);
                const float4 u1 = *(const float4*)(A + (size_t)gr * K + kk * 32 + quad * 8 + 4);
                aReg[mi][kk][0] = (_Float16)u0.x; aReg[mi][kk][1] = (_Float16)u0.y;
                aReg[mi][kk][2] = (_Float16)u0.z; aReg[mi][kk][3] = (_Float16)u0.w;
                aReg[mi][kk][4] = (_Float16)u1.x; aReg[mi][kk][5] = (_Float16)u1.y;
                aReg[mi][kk][6] = (_Float16)u1.z; aReg[mi][kk][7] = (_Float16)u1.w;
            }
        }
    } else {
        const _Float16* A = (const _Float16*)Av;
        #pragma unroll
        for (int mi = 0; mi < 2; ++mi) {
            const int gr = mi ? gr1 : gr0;
            #pragma unroll
            for (int kk = 0; kk < 8; ++kk)
                aReg[mi][kk] = *(const half8*)(A + (size_t)gr * K + kk * 32 + quad * 8);
        }
    }

    f32x4 acc[2][16] = {};

    #pragma unroll
    for (int hf = 0; hf < 2; ++hf) {
        if (hf) __syncthreads();            // all waves done reading half-0 Bs
        // stage B half: 128 n x 256 k (coalesced; 16 chunks/thread)
        #pragma unroll
        for (int c = 0; c < 16; ++c) {
            const int idx = c * 256 + tid;
            const int n   = idx >> 5;
            const int ko  = (idx & 31) * 8;
            *(half8*)&Bs[n * LDB + ko] =
                *(const half8*)(Wt + (size_t)(hf * 128 + n) * K + ko);
        }
        __syncthreads();

        #pragma unroll
        for (int kk = 0; kk < 8; ++kk) {
            #pragma unroll
            for (int ni = 0; ni < 8; ++ni) {
                const half8 bf = *(const half8*)&Bs[(ni * 16 + l16) * LDB + kk * 32 + quad * 8];
                acc[0][hf * 8 + ni] = __builtin_amdgcn_mfma_f32_16x16x32_f16(
                    aReg[0][kk], bf, acc[0][hf * 8 + ni], 0, 0, 0);
                acc[1][hf * 8 + ni] = __builtin_amdgcn_mfma_f32_16x16x32_f16(
                    aReg[1][kk], bf, acc[1][hf * 8 + ni], 0, 0, 0);
            }
        }
    }

    // epilogue: C/D layout col=lane&15, row=quad*4+reg
    #pragma unroll
    for (int ci = 0; ci < 16; ++ci) {
        const int col = ci * 16 + l16;
        const float b = bias[col];
        #pragma unroll
        for (int mi = 0; mi < 2; ++mi) {
            #pragma unroll
            for (int r = 0; r < 4; ++r) {
                const int grow = row0 + wave * 32 + mi * 16 + quad * 4 + r;
                if (grow < M) {
                    const float v = fmaxf(acc[mi][ci][r] + b, 0.f);
                    out[(size_t)grow * K + col] = (_Float16)v;
                }
            }
        }
    }
}

// --- MFMA FC: logits[M x 40] = h[M x 256] @ wfcT^T + bfc  (no relu)
__global__ __launch_bounds__(256, 2) void fc_mfma(
    const _Float16* __restrict__ h, const _Float16* __restrict__ WfcT,
    const float* __restrict__ bfc, float* __restrict__ logits, int M)
{
    constexpr int K = 256;
    constexpr int LDB = 264;
    __shared__ _Float16 Bs[48 * LDB];

    const int tid  = threadIdx.x;
    const int wave = tid >> 6;
    const int lane = tid & 63;
    const int quad = lane >> 4;
    const int l16  = lane & 15;
    const int row0 = blockIdx.x * 128;

    #pragma unroll
    for (int c = 0; c < 6; ++c) {
        const int idx = c * 256 + tid;
        const int n   = idx >> 5;
        const int ko  = (idx & 31) * 8;
        *(half8*)&Bs[n * LDB + ko] = *(const half8*)(WfcT + (size_t)n * K + ko);
    }
    __syncthreads();

    const int gr0 = min(row0 + wave * 32 + l16,      M - 1);
    const int gr1 = min(row0 + wave * 32 + 16 + l16, M - 1);

    f32x4 acc[2][3] = {};

    for (int k0 = 0; k0 < K; k0 += 32) {
        half8 af[2];
        af[0] = *(const half8*)(h + (size_t)gr0 * K + k0 + quad * 8);
        af[1] = *(const half8*)(h + (size_t)gr1 * K + k0 + quad * 8);
        #pragma unroll
        for (int ni = 0; ni < 3; ++ni) {
            const half8 bf = *(const half8*)&Bs[(ni * 16 + l16) * LDB + k0 + quad * 8];
            acc[0][ni] = __builtin_amdgcn_mfma_f32_16x16x32_f16(af[0], bf, acc[0][ni], 0, 0, 0);
            acc[1][ni] = __builtin_amdgcn_mfma_f32_16x16x32_f16(af[1], bf, acc[1][ni], 0, 0, 0);
        }
    }

    #pragma unroll
    for (int ni = 0; ni < 3; ++ni) {
        const int col = ni * 16 + l16;
        if (col >= C_DIM) continue;
        const float b = bfc[col];
        #pragma unroll
        for (int mi = 0; mi < 2; ++mi) {
            #pragma unroll
            for (int r = 0; r < 4; ++r) {
                const int grow = row0 + wave * 32 + mi * 16 + quad * 4 + r;
                if (grow < M)
                    logits[(size_t)grow * C_DIM + col] = acc[mi][ni][r] + b;
            }
        }
    }
}

// --- exclusive scan, int4/thread (single workgroup); writes rowptr AND cursor
__global__ __launch_bounds__(1024) void scan_deg4(
    const int* __restrict__ deg, int* __restrict__ rowptr,
    int* __restrict__ cursor, int N)
{
    __shared__ int waveSums[16];
    __shared__ int carrySh;
    const int tid  = threadIdx.x;
    const int lane = tid & 63;
    const int wid  = tid >> 6;
    const int N4 = N >> 2;                  // N divisible by 4
    if (tid == 0) carrySh = 0;
    __syncthreads();
    for (int base = 0; base < N4; base += 1024) {
        const int i4 = base + tid;
        int4 v = make_int4(0, 0, 0, 0);
        if (i4 < N4) v = ((const int4*)deg)[i4];
        const int tsum = v.x + v.y + v.z + v.w;
        int s = tsum;
        #pragma unroll
        for (int off = 1; off < 64; off <<= 1) {
            const int t = __shfl_up(s, off, 64);
            if (lane >= off) s += t;
        }
        if (lane == 63) waveSums[wid] = s;
        __syncthreads();
        if (wid == 0) {
            const int ws = (lane < 16) ? waveSums[lane] : 0;
            int ss = ws;
            #pragma unroll
            for (int off = 1; off < 16; off <<= 1) {
                const int t = __shfl_up(ss, off, 64);
                if (lane >= off) ss += t;
            }
            if (lane < 16) waveSums[lane] = ss - ws;   // exclusive
        }
        __syncthreads();
        const int carry = carrySh;
        if (i4 < N4) {
            const int e0 = carry + waveSums[wid] + (s - tsum);
            int4 o;
            o.x = e0;
            o.y = e0 + v.x;
            o.z = e0 + v.x + v.y;
            o.w = e0 + v.x + v.y + v.z;
            ((int4*)rowptr)[i4] = o;
            ((int4*)cursor)[i4] = o;
        }
        __syncthreads();
        if (tid == 1023) carrySh = carry + waveSums[15] + s;
        __syncthreads();
    }
    if (tid == 0) rowptr[N] = carrySh;
}

// --- bucket CSR: LDS-reorder chunk by bucket, emit contiguous runs.
//     packed edge = (src<<8) | (dst&255). Counts come from cntMat.
__global__ __launch_bounds__(256) void bucket_scatter(
    const int* __restrict__ src, const int* __restrict__ dst,
    const int* __restrict__ cntMat, const int* __restrict__ baseMat,
    int* __restrict__ packed, int E, int chunk)
{
    __shared__ int lcnt[NBUCK], loff[NBUCK], cursor[NBUCK], gbase[NBUCK];
    __shared__ int segSum[4];
    __shared__ int ldsOut[MAXCHUNK];
    const int tid  = threadIdx.x;
    const int wave = tid >> 6;
    const int lane = tid & 63;
    const int k    = blockIdx.x;
    const int e0 = k * chunk;
    const int e1 = min(e0 + chunk, E);

    lcnt[tid]  = cntMat[tid * NB + k];
    gbase[tid] = baseMat[tid * NB + k];
    __syncthreads();

    // exclusive scan lcnt -> loff (4 waves x 64)
    {
        const int v = lcnt[tid];
        int s = v;
        #pragma unroll
        for (int off = 1; off < 64; off <<= 1) {
            const int t = __shfl_up(s, off, 64);
            if (lane >= off) s += t;
        }
        loff[tid] = s - v;
        if (lane == 63) segSum[wave] = s;
    }
    __syncthreads();
    if (tid == 0) {
        int c = 0;
        #pragma unroll
        for (int w = 0; w < 4; ++w) { const int t = segSum[w]; segSum[w] = c; c += t; }
    }
    __syncthreads();
    loff[tid] += segSum[wave];
    cursor[tid] = 0;
    __syncthreads();

    // read chunk, place packed values bucket-ordered in LDS
    for (int i = e0 + tid; i < e1; i += 256) {
        const int d = dst[i];
        const int b = d >> 8;
        const int pos = atomicAdd(&cursor[b], 1);
        ldsOut[loff[b] + pos] = (src[i] << 8) | (d & 255);
    }
    __syncthreads();

    // emit each bucket's run contiguously (wave per bucket rr)
    for (int b = wave; b < NBUCK; b += 4) {
        const int cnt = lcnt[b];
        const int gb  = gbase[b];
        const int lb  = loff[b];
        for (int j = lane; j < cnt; j += 64)
            packed[gb + j] = ldsOut[lb + j];
    }
}

// --- bucket CSR: per-bucket node histogram -> rowptr + ordered csr_src
__global__ __launch_bounds__(256) void bucket_to_csr(
    const int* __restrict__ packed, const int* __restrict__ baseMat,
    int* __restrict__ rowptr, int* __restrict__ csr_src, int N)
{
    __shared__ int lcnt[NBUCK], loff[NBUCK], cursor[NBUCK];
    __shared__ int segSum[4];
    const int tid  = threadIdx.x;
    const int wave = tid >> 6;
    const int lane = tid & 63;
    const int b    = blockIdx.x;
    const int gbeg = baseMat[b * NB];
    const int gend = baseMat[(b + 1) * NB];

    const int nodeBase = b * NBUCK;
    if (nodeBase > N) return;               // bucket beyond node range

    lcnt[tid] = 0;
    __syncthreads();

    // histogram of low-8 node ids
    for (int e = gbeg + tid; e < gend; e += 256)
        atomicAdd(&lcnt[packed[e] & 255], 1);
    __syncthreads();

    // exclusive scan lcnt -> loff
    {
        const int v = lcnt[tid];
        int s = v;
        #pragma unroll
        for (int off = 1; off < 64; off <<= 1) {
            const int t = __shfl_up(s, off, 64);
            if (lane >= off) s += t;
        }
        loff[tid] = s - v;
        if (lane == 63) segSum[wave] = s;
    }
    __syncthreads();
    if (tid == 0) {
        int c = 0;
        #pragma unroll
        for (int w = 0; w < 4; ++w) { const int t = segSum[w]; segSum[w] = c; c += t; }
    }
    __syncthreads();
    loff[tid] += segSum[wave];
    cursor[tid] = 0;
    __syncthreads();

    // rowptr for owned nodes
    if (nodeBase + tid <= N)
        rowptr[nodeBase + tid] = gbeg + loff[tid];
    __syncthreads();

    // scatter src ids ordered by node (block-owned region)
    for (int e = gbeg + tid; e < gend; e += 256) {
        const int p = packed[e];
        const int node = p & 255;
        const int pos = atomicAdd(&cursor[node], 1);
        csr_src[gbeg + loff[node] + pos] = p >> 8;
    }
}

// --- conv aggregate: h[row] = f16(relu(msg[row] + sum_{in-edges} msg[src]))
//     2 rows per wave (32 lanes x half8 each); edge loop unrolled x8.
__global__ __launch_bounds__(512) void csr_gather_f16(
    const _Float16* __restrict__ msg, const int* __restrict__ rowptr,
    const int* __restrict__ csr_src, _Float16* __restrict__ h, int N)
{
    const int tid  = threadIdx.x;
    const int wave = tid >> 6;
    const int lane = tid & 63;
    const int g    = lane >> 5;              // row within wave (0/1)
    const int rl   = lane & 31;              // lane within row-group
    const int gsrc = lane & 32;              // shuffle base of this group
    const int row  = (blockIdx.x * 8 + wave) * 2 + g;
    if (row >= N) return;

    const int beg = rowptr[row];
    const int end = rowptr[row + 1];
    const size_t fofs = (size_t)rl * 8;

    const half8 self = *(const half8*)(msg + (size_t)row * F_DIM + fofs);
    float a[8];
    #pragma unroll
    for (int i = 0; i < 8; ++i) a[i] = (float)self[i];

    for (int e0 = beg; e0 < end; e0 += 32) {
        const int n  = min(32, end - e0);
        const int sv = (e0 + rl < end) ? csr_src[e0 + rl] : 0;
        int j = 0;
        for (; j + 8 <= n; j += 8) {
            int s[8];
            #pragma unroll
            for (int u = 0; u < 8; ++u) s[u] = __shfl(sv, gsrc + j + u, 64);
            half8 v[8];
            #pragma unroll
            for (int u = 0; u < 8; ++u)
                v[u] = *(const half8*)(msg + (size_t)s[u] * F_DIM + fofs);
            #pragma unroll
            for (int u = 0; u < 8; ++u)
                #pragma unroll
                for (int i = 0; i < 8; ++i) a[i] += (float)v[u][i];
        }
        for (; j < n; ++j) {
            const int s = __shfl(sv, gsrc + j, 64);
            const half8 v = *(const half8*)(msg + (size_t)s * F_DIM + fofs);
            #pragma unroll
            for (int i = 0; i < 8; ++i) a[i] += (float)v[i];
        }
    }

    half8 o;
    #pragma unroll
    for (int i = 0; i < 8; ++i) o[i] = (_Float16)fmaxf(a[i], 0.f);
    *(half8*)(h + (size_t)row * F_DIM + fofs) = o;
}

// --- sparse PvT: out[prow[i]] += pval[i] * logits[pcol[i]], wave/nnz
__global__ __launch_bounds__(256) void pvt_scatter(
    const float* __restrict__ logits, const int* __restrict__ prow,
    const int* __restrict__ pcol, const float* __restrict__ pval,
    float* __restrict__ out, int nnz)
{
    const int i    = (blockIdx.x * 256 + threadIdx.x) >> 6;
    const int lane = threadIdx.x & 63;
    if (i >= nnz || lane >= C_DIM) return;
    const int r = prow[i];
    const int c = pcol[i];
    const float v = pval[i];
    atomicAdd(out + (size_t)r * C_DIM + lane, v * logits[(size_t)c * C_DIM + lane]);
}

// --- row-wise log_softmax in place, wave/row (lanes 0..39 active)
__global__ __launch_bounds__(256) void log_softmax40(float* __restrict__ out, int M)
{
    const int row  = (blockIdx.x * 256 + threadIdx.x) >> 6;
    const int lane = threadIdx.x & 63;
    if (row >= M) return;
    const float v = (lane < C_DIM) ? out[(size_t)row * C_DIM + lane] : -INFINITY;
    float m = v;
    #pragma unroll
    for (int off = 32; off >= 1; off >>= 1)
        m = fmaxf(m, __shfl_xor(m, off, 64));
    float e = (lane < C_DIM) ? expf(v - m) : 0.f;
    float s = e;
    #pragma unroll
    for (int off = 32; off >= 1; off >>= 1)
        s += __shfl_xor(s, off, 64);
    if (lane < C_DIM)
        out[(size_t)row * C_DIM + lane] = v - m - logf(s);
}

extern "C" void kernel_launch(void* const* d_in, const int* in_sizes, int n_in,
                              void* d_out, int out_size, void* d_ws, size_t ws_size,
                              hipStream_t stream)
{
    const float* x        = (const float*)d_in[0];
    const int*   edge_src = (const int*)d_in[1];
    const int*   edge_dst = (const int*)d_in[2];
    const int*   pvt_row  = (const int*)d_in[3];
    const int*   pvt_col  = (const int*)d_in[4];
    const float* pvt_val  = (const float*)d_in[5];
    const float* w1       = (const float*)d_in[6];
    const float* b1       = (const float*)d_in[7];
    const float* w2       = (const float*)d_in[8];
    const float* b2       = (const float*)d_in[9];
    const float* wfc      = (const float*)d_in[10];
    const float* bfc      = (const float*)d_in[11];

    const int N   = in_sizes[0] / F_DIM;   // 50000
    const int E   = in_sizes[1];           // 1600000
    const int NNZ = in_sizes[3];           // 50000

    float* out = (float*)d_out;

    // workspace layout
    const size_t nodeElems = (size_t)N * F_DIM;
    _Float16* w1t     = (_Float16*)d_ws;              // 256*256 fp16
    _Float16* w2t     = w1t + 65536;                  // 256*256 fp16
    _Float16* wfcT    = w2t + 65536;                  // 48*256 fp16
    _Float16* bufM    = wfcT + 48 * 256;              // msg, N*256 fp16
    _Float16* bufH    = bufM + nodeElems;             // h,   N*256 fp16
    float*    logits  = (float*)(bufH + nodeElems);   // N x 40 f32
    int*      cntMat  = (int*)(logits + (size_t)N * C_DIM); // 65536
    int*      baseMat = cntMat + 65536;               // 65537 (+pad)
    int*      rowptr  = baseMat + 65544;              // N+1 (+pad)
    int*      csr_src = rowptr + N + 8;               // E
    int*      packed  = csr_src + E;                  // E

    const int chunk = (E + NB - 1) / NB;              // 6250, <= MAXCHUNK

    const int gemmBlocks  = (N + 127) / 128;
    const int fcBlocks    = (N + 127) / 128;
    const int rowBlocks   = (N + 3) / 4;
    const int gatherBlocks= (N + 15) / 16;            // 16 rows per 512-blk
    const int nnzBlocks   = (NNZ + 3) / 4;

    // === prep: bucket histograms + weight conversions (one kernel) ===
    prep<<<NB + 768, 256, 0, stream>>>(edge_dst, cntMat, E, chunk,
                                       w1, w2, wfc, w1t, w2t, wfcT);

    // === bucket-sort CSR build ===
    scan_deg4<<<1, 1024, 0, stream>>>(cntMat, baseMat, baseMat, NBUCK * NB);
    bucket_scatter<<<NB, 256, 0, stream>>>(edge_src, edge_dst, cntMat, baseMat,
                                           packed, E, chunk);
    bucket_to_csr<<<NBUCK, 256, 0, stream>>>(packed, baseMat, rowptr, csr_src, N);

    // === layer 1 (A = fp32 x, converted inline) ===
    gemm_f16<true><<<gemmBlocks, 256, 0, stream>>>(x, w1t, b1, bufM, N);
    csr_gather_f16<<<gatherBlocks, 512, 0, stream>>>(bufM, rowptr, csr_src, bufH, N);

    // === layer 2 ===
    gemm_f16<false><<<gemmBlocks, 256, 0, stream>>>(bufH, w2t, b2, bufM, N);
    csr_gather_f16<<<gatherBlocks, 512, 0, stream>>>(bufM, rowptr, csr_src, bufH, N);

    // === FC (MFMA) ===
    fc_mfma<<<fcBlocks, 256, 0, stream>>>(bufH, wfcT, bfc, logits, N);

    // === PvT scatter into d_out, then log_softmax ===
    hipMemsetAsync(d_out, 0, (size_t)N * C_DIM * sizeof(float), stream);
    pvt_scatter<<<nnzBlocks, 256, 0, stream>>>(logits, pvt_row, pvt_col, pvt_val, out, NNZ);
    log_softmax40<<<rowBlocks, 256, 0, stream>>>(out, N);
}